// Round 18
// baseline (113.675 us; speedup 1.0000x reference)
//
#include <hip/hip_runtime.h>
#include <hip/hip_bf16.h>

// Problem constants: E=1024, H=16, HD=64, T=1024, B=4, S=1024.
// d_out: attn(T,B,E) f32 [4M floats] then avg_w(B,T,S) f32 [4M floats].
// ws layout (bytes): qh 0..8M (head-major [bh][t][64], q pre-scaled 0.125*log2e),
//   kh 8..16M, vf 24..32M (frag-swizzled V, proj cmode3 LDS-coalesced epilogue),
//   ab 32..40M, WT 40..46M, owb 46..48M.
// Overlays (dead-interval reuse): qin = ws+16M, kin = ws+32M (ab written later
//   by attn_avg), vin = d_out+16MB (avg region written later by attn_avg).
// avg_w is computed INSIDE the attn launch (blocks >= 1024) for overlap.

typedef __bf16 bf16;
typedef float f32x4 __attribute__((ext_vector_type(4)));
typedef float float4v __attribute__((ext_vector_type(4)));
typedef bf16 bf16x8 __attribute__((ext_vector_type(8)));
typedef bf16 bf16x4 __attribute__((ext_vector_type(4)));

#define LOG2E 1.4426950408889634f

// async global->LDS, 16B/lane; dst base wave-uniform (HW adds lane*16).
__device__ __forceinline__ void gll16(const void* g, void* l) {
  __builtin_amdgcn_global_load_lds(
      (const __attribute__((address_space(1))) void*)g,
      (__attribute__((address_space(3))) void*)l, 16, 0, 0);
}

// XCD-chunked swizzle: consecutive works (sharing an A-panel) land on one XCD.
__device__ __forceinline__ int xcd_swz(int flat, int nwg) {
  int q = nwg >> 3;
  return (flat & 7) * q + (flat >> 3);
}

__device__ __forceinline__ bf16x4 cvt4(float4v v) {
  bf16x4 b = { (bf16)v.x, (bf16)v.y, (bf16)v.z, (bf16)v.w };
  return b;
}

// ---------------- fused prep kernel ----------------
// blocks [0,4096): q conv ; [4096,8192): k ; [8192,12288): v ;
// [12288,13056): W transpose (16x16x3) ; [13056,14080): out_w conv.
__device__ __forceinline__ void conv_body(const float* __restrict__ src,
                                          bf16* __restrict__ dst, int bid) {
  int i = (bid * 256 + (int)threadIdx.x) * 4;
  float4v v = *(const float4v*)(src + i);
  *(bf16x4*)&dst[i] = cvt4(v);
}

__global__ __launch_bounds__(256) void prep_all(
    const float* __restrict__ q, const float* __restrict__ k,
    const float* __restrict__ v, const float* __restrict__ W,
    const float* __restrict__ out_w,
    bf16* __restrict__ qin, bf16* __restrict__ kin, bf16* __restrict__ vin,
    bf16* __restrict__ WT, bf16* __restrict__ owb) {
  __shared__ bf16 tile[64][72];
  int bid = blockIdx.x;
  if (bid < 4096) { conv_body(q, qin, bid); return; }
  if (bid < 8192) { conv_body(k, kin, bid - 4096); return; }
  if (bid < 12288) { conv_body(v, vin, bid - 8192); return; }
  if (bid >= 13056) { conv_body(out_w, owb, bid - 13056); return; }
  // W transpose: dst[sec][j][i] = (bf16) src[sec*1024 + i][j]
  int idx = bid - 12288;
  int sec = idx >> 8, bx = idx & 15, by = (idx >> 4) & 15;
  int i0 = by * 64, j0 = bx * 64;
  const float* s = W + (long)sec * 1048576;
  bf16* d = WT + (long)sec * 1048576;
  int t = threadIdx.x;
#pragma unroll
  for (int p = 0; p < 4; p++) {
    int ri = (t >> 4) + p * 16, cj = (t & 15) * 4;
    float4v vv = *(const float4v*)(s + (long)(i0 + ri) * 1024 + j0 + cj);
    *(bf16x4*)&tile[ri][cj] = cvt4(vv);
  }
  __syncthreads();
#pragma unroll
  for (int p = 0; p < 4; p++) {
    int rj = (t >> 4) + p * 16, ci = (t & 15) * 4;
    bf16x4 bv = { tile[ci][rj], tile[ci + 1][rj], tile[ci + 2][rj], tile[ci + 3][rj] };
    *(bf16x4*)&d[(long)(j0 + rj) * 1024 + i0 + ci] = bv;
  }
}

// ---------------- unified bf16 NT GEMM core (512 thr, 8 waves, 128x128) ----
// R11-best loop: double-buffered, stage(next) issued BEFORE compute(cur), ONE
// __syncthreads per k-step. cmode: 0 f32 std, 1 bf16 std, 2 bf16 head-major,
// 3 vf fragment layout via LDS-coalesced epilogue (R15-verified).
__device__ __forceinline__ void gemm_core(
    const bf16* __restrict__ A, long lda,
    const bf16* __restrict__ B, long ldb,
    void* __restrict__ C, long ldc,
    const float* __restrict__ bias, float scale, int K,
    int m0, int n0, int cmode) {
  __shared__ bf16 smem[16384];  // sA[2][4096] | sB[2][4096]; epilogue overlay
  bf16 (*sA)[4096] = (bf16(*)[4096])smem;
  bf16 (*sB)[4096] = (bf16(*)[4096])(smem + 8192);
  int t = threadIdx.x;
  int w = t >> 6, lane = t & 63, r = lane & 15, g = lane >> 4;
  int mq = (w >> 1) * 32, nq = (w & 1) * 64;
  int srow = w * 16 + (lane >> 2);
  int scol = ((lane & 3) ^ ((srow >> 1) & 3)) * 8;
  int fsw = (r >> 1) & 3;
  const bf16* As = A + (long)(m0 + srow) * lda + scol;
  const bf16* Bs = B + (long)(n0 + srow) * ldb + scol;

  f32x4 acc[2][4];
#pragma unroll
  for (int mi = 0; mi < 2; mi++)
#pragma unroll
    for (int ni = 0; ni < 4; ni++) acc[mi][ni] = (f32x4){0.f, 0.f, 0.f, 0.f};

  gll16(As, &sA[0][w * 512]);
  gll16(Bs, &sB[0][w * 512]);
  __syncthreads();
  int cur = 0;
  for (int k0 = 0; k0 < K; k0 += 32) {
    if (k0 + 32 < K) {
      gll16(As + k0 + 32, &sA[cur ^ 1][w * 512]);
      gll16(Bs + k0 + 32, &sB[cur ^ 1][w * 512]);
    }
    bf16x8 af[2], bfr[4];
#pragma unroll
    for (int mi = 0; mi < 2; mi++)
      af[mi] = *(bf16x8*)&sA[cur][(mq + mi * 16 + r) * 32 + 8 * (g ^ fsw)];
#pragma unroll
    for (int ni = 0; ni < 4; ni++)
      bfr[ni] = *(bf16x8*)&sB[cur][(nq + ni * 16 + r) * 32 + 8 * (g ^ fsw)];
#pragma unroll
    for (int mi = 0; mi < 2; mi++)
#pragma unroll
      for (int ni = 0; ni < 4; ni++)
        acc[mi][ni] = __builtin_amdgcn_mfma_f32_16x16x32_bf16(af[mi], bfr[ni], acc[mi][ni], 0, 0, 0);
    __syncthreads();
    cur ^= 1;
  }

  if (cmode == 3) {
    // acc -> LDS in vf order -> coalesced 1KB/wave stores (R15-verified map).
#pragma unroll
    for (int mi = 0; mi < 2; mi++) {
      int s32 = (mq >> 2) + mi * 4 + g;
      int gq = (s32 >> 2) & 3;
      int u = ((s32 >> 4) << 2) | (s32 & 3);
#pragma unroll
      for (int ni = 0; ni < 4; ni++) {
        int col = n0 + nq + ni * 16 + r;
        float bv = bias ? bias[col] : 0.f;
        int clbase = ((nq >> 5) + (ni >> 1)) * 2 + (ni & 1);
#pragma unroll
        for (int j = 0; j < 4; j++) {
          float val = (acc[mi][ni][j] + bv) * scale;
          smem[(j * 8 + clbase) * 512 + (gq * 16 + r) * 8 + u] = (bf16)val;
        }
      }
    }
    __syncthreads();
    int sc_ = m0 >> 7;
    int hh0 = (n0 & 511) >> 5;
    int half = n0 >> 9;
#pragma unroll
    for (int c = 0; c < 4; c++) {
      int cl = w * 4 + c;
      int b_ = cl >> 3, hl = (cl >> 1) & 3, dl = cl & 1;
      long chunk = ((long)(b_ * 16 + hh0 + hl) * 32 + sc_) * 4 + half * 2 + dl;
      bf16x8 v = *(bf16x8*)&smem[cl * 512 + lane * 8];
      *(bf16x8*)&((bf16*)C)[(chunk << 9) + lane * 8] = v;
    }
    return;
  }

#pragma unroll
  for (int mi = 0; mi < 2; mi++)
#pragma unroll
    for (int ni = 0; ni < 4; ni++) {
      int col = n0 + nq + ni * 16 + r;
      float bv = bias ? bias[col] : 0.f;
#pragma unroll
      for (int j = 0; j < 4; j++) {
        int row = m0 + mq + mi * 16 + g * 4 + j;
        float val = (acc[mi][ni][j] + bv) * scale;
        if (cmode == 2) {
          int bb = row & 3, tt = row >> 2, hh = col >> 6, dd = col & 63;
          ((bf16*)C)[((long)(bb * 16 + hh) * 1024 + tt) * 64 + dd] = (bf16)val;
        } else if (cmode == 1) {
          ((bf16*)C)[(long)row * ldc + col] = (bf16)val;
        } else {
          ((float*)C)[(long)row * ldc + col] = val;
        }
      }
    }
}

// out-projection (cmode 0)
__global__ __launch_bounds__(512) void gemm_out(
    const bf16* __restrict__ A, const bf16* __restrict__ B,
    float* __restrict__ C, const float* __restrict__ bias) {
  int nwg = gridDim.x * gridDim.y;
  int flat = blockIdx.x + gridDim.x * blockIdx.y;
  int work = xcd_swz(flat, nwg);
  int n = work % gridDim.x, m = work / gridDim.x;
  gemm_core(A, 1024, B, 1024, C, 1024, bias, 1.0f, 1024, m * 128, n * 128, 0);
}

// fused q/k/v projection from pre-converted bf16 inputs; v (z=2) -> vf (cmode 3)
__global__ __launch_bounds__(512) void gemm_proj(
    const bf16* __restrict__ qin, const bf16* __restrict__ kin,
    const bf16* __restrict__ vin, const bf16* __restrict__ WT,
    const float* __restrict__ bias, bf16* __restrict__ qkout,
    bf16* __restrict__ vf) {
  int nwg = gridDim.x * gridDim.y * gridDim.z;
  int flat = blockIdx.x + gridDim.x * (blockIdx.y + gridDim.y * blockIdx.z);
  int work = xcd_swz(flat, nwg);
  int n = work % gridDim.x;
  int m = (work / gridDim.x) % gridDim.y;
  int z = work / (gridDim.x * gridDim.y);
  const bf16* A = (z == 0) ? qin : ((z == 1) ? kin : vin);
  const bf16* B = WT + (long)z * 1048576;
  const float* bz = bias + z * 1024;
  void* C = (z == 2) ? (void*)vf : (void*)(qkout + (long)z * 4194304);
  float scale = (z == 0) ? 0.125f * LOG2E : 1.0f;
  gemm_core(A, 1024, B, 1024, C, 1024, bz, scale, 1024, m * 128, n * 128,
            z == 2 ? 3 : 2);
}

// ---------------- fused attention + avg_w (one launch, 256 thr) -------------
// blocks [0,1024): attn v12 (bh = bid%64, t0 = bid/64).
// blocks [1024,1536): avg_w 64x128-tile GEMM over head-major qh/kh.
// Shared 32KB LDS arena unioned across the two bodies -> 5 blocks/CU.
__global__ __launch_bounds__(256) void attn_avg(
    const bf16* __restrict__ qh, const bf16* __restrict__ kh,
    const bf16* __restrict__ vf, bf16* __restrict__ attn_b,
    float* __restrict__ out_avg, float avg_scale) {
  __shared__ __align__(16) bf16 smem[16384];  // 32 KB arena
  int tid = threadIdx.x, w = tid >> 6, lane = tid & 63, r = lane & 15, g = lane >> 4;
  int fsw = (r >> 1) & 3;

  if (blockIdx.x >= 1024) {
    // ---------- avg_w: C[bb][t][s] = avg_scale * sum_e qh[t][e] kh[s][e] ----
    bf16* sA = smem;            // [2][2048]
    bf16* sB = smem + 4096;     // [2][4096]
    int work = xcd_swz(blockIdx.x - 1024, 512);
    int n0 = (work & 7) * 128;
    int m0 = ((work >> 3) & 15) * 64;
    int bb = work >> 7;
    int mq = (w >> 1) * 32, nq = (w & 1) * 64;
    int srow = w * 16 + (lane >> 2);            // 0..63
    int scol = ((lane & 3) ^ ((srow >> 1) & 3)) * 8;
    const bf16* Asb = qh + (long)bb * 1048576 + (long)(m0 + srow) * 64 + scol;
    const bf16* Bs0 = kh + (long)bb * 1048576 + (long)(n0 + srow) * 64 + scol;
    const bf16* Bs1 = kh + (long)bb * 1048576 + (long)(n0 + srow + 64) * 64 + scol;

    f32x4 acc[2][4];
#pragma unroll
    for (int mi = 0; mi < 2; mi++)
#pragma unroll
      for (int ni = 0; ni < 4; ni++) acc[mi][ni] = (f32x4){0.f, 0.f, 0.f, 0.f};

    auto stage = [&](int buf, long off) {
      gll16(Asb + off, &sA[buf * 2048 + w * 512]);
      gll16(Bs0 + off, &sB[buf * 4096 + w * 512]);
      gll16(Bs1 + off, &sB[buf * 4096 + 2048 + w * 512]);
    };
    stage(0, 0);
    __syncthreads();
    int cur = 0;
    for (int k0 = 0; k0 < 1024; k0 += 32) {
      if (k0 + 32 < 1024) {
        int kn = k0 + 32;
        stage(cur ^ 1, ((long)(kn >> 6)) * 65536 + (kn & 63));
      }
      bf16x8 af[2], bfr[4];
#pragma unroll
      for (int mi = 0; mi < 2; mi++)
        af[mi] = *(bf16x8*)&sA[cur * 2048 + (mq + mi * 16 + r) * 32 + 8 * (g ^ fsw)];
#pragma unroll
      for (int ni = 0; ni < 4; ni++)
        bfr[ni] = *(bf16x8*)&sB[cur * 4096 + (nq + ni * 16 + r) * 32 + 8 * (g ^ fsw)];
#pragma unroll
      for (int mi = 0; mi < 2; mi++)
#pragma unroll
        for (int ni = 0; ni < 4; ni++)
          acc[mi][ni] = __builtin_amdgcn_mfma_f32_16x16x32_bf16(af[mi], bfr[ni], acc[mi][ni], 0, 0, 0);
      __syncthreads();
      cur ^= 1;
    }
#pragma unroll
    for (int mi = 0; mi < 2; mi++)
#pragma unroll
      for (int ni = 0; ni < 4; ni++) {
        int col = n0 + nq + ni * 16 + r;
#pragma unroll
        for (int j = 0; j < 4; j++) {
          int row = m0 + mq + mi * 16 + g * 4 + j;
          out_avg[(long)bb * 1048576 + (long)row * 1024 + col] = acc[mi][ni][j] * avg_scale;
        }
      }
    return;
  }

  // ---------- attn (v12): 4 waves, 16 t-rows/wave, full-S sweep ----------
  bf16* sK = smem;            // [2][4096]
  bf16* sV = smem + 8192;     // [2][4096]
  int bh = blockIdx.x & 63;
  int b = bh >> 4, h = bh & 15;
  int t0 = (blockIdx.x >> 6) * 64;
  int tw = t0 + w * 16;

  const bf16* qrow = qh + ((long)bh * 1024 + tw + r) * 64;
  bf16x8 aq0 = *(const bf16x8*)(qrow + g * 8);
  bf16x8 aq1 = *(const bf16x8*)(qrow + 32 + g * 8);

  float sp_acc = 0.f, sn_acc = 0.f;
  f32x4 o[4];
#pragma unroll
  for (int d = 0; d < 4; d++) o[d] = (f32x4){0.f, 0.f, 0.f, 0.f};

  const bf16* kbh = kh + (long)bh * 65536;
  const bf16* vbh = vf + (long)bh * 65536;

  int krow = w * 16 + (lane >> 3);
  const bf16* ksrc = kbh + (long)krow * 64 + 8 * ((lane & 7) ^ (krow & 7));
  const bf16* vsrc = vbh + w * 1024 + lane * 8;
  int c0 = 8 * (g ^ (r & 7));
  int c1 = 8 * ((g + 4) ^ (r & 7));

  auto stage = [&](int buf, int st) {
    const bf16* kp = ksrc + st * 4096;
    gll16(kp, &sK[buf * 4096 + w * 1024]);
    gll16(kp + 512, &sK[buf * 4096 + w * 1024 + 512]);
    const bf16* vp = vsrc + st * 4096;
    gll16(vp, &sV[buf * 4096 + w * 1024]);
    gll16(vp + 512, &sV[buf * 4096 + w * 1024 + 512]);
  };
  stage(0, 0);
  __syncthreads();
  int cur = 0;
#pragma unroll 1
  for (int st = 0; st < 16; st++) {
    if (st < 15) stage(cur ^ 1, st + 1);
    f32x4 sc4[4];
#pragma unroll
    for (int sf = 0; sf < 4; sf++) {
      int row = sf * 16 + r;
      bf16x8 k0 = *(const bf16x8*)&sK[cur * 4096 + row * 64 + c0];
      bf16x8 k1 = *(const bf16x8*)&sK[cur * 4096 + row * 64 + c1];
      f32x4 z = (f32x4){0.f, 0.f, 0.f, 0.f};
      z = __builtin_amdgcn_mfma_f32_16x16x32_bf16(k0, aq0, z, 0, 0, 0);
      z = __builtin_amdgcn_mfma_f32_16x16x32_bf16(k1, aq1, z, 0, 0, 0);
      sc4[sf] = z;
    }
    bf16x8 pP[2], pN[2];
#pragma unroll
    for (int sf = 0; sf < 4; sf++)
#pragma unroll
      for (int j = 0; j < 4; j++) {
        float e = __builtin_amdgcn_exp2f(sc4[sf][j]);
        sp_acc += e;
        pP[sf >> 1][(sf & 1) * 4 + j] = (bf16)e;
        float f = __builtin_amdgcn_exp2f(-sc4[sf][j]);
        sn_acc += f;
        pN[sf >> 1][(sf & 1) * 4 + j] = (bf16)f;
      }
#pragma unroll
    for (int c = 0; c < 2; c++)
#pragma unroll
      for (int dblk = 0; dblk < 4; dblk++) {
        bf16x8 vv = *(const bf16x8*)&sV[cur * 4096 + (c * 4 + dblk) * 512 + lane * 8];
        o[dblk] = __builtin_amdgcn_mfma_f32_16x16x32_bf16(
            vv, (dblk < 2) ? pP[c] : pN[c], o[dblk], 0, 0, 0);
      }
    __syncthreads();
    cur ^= 1;
  }

  sp_acc += __shfl_xor(sp_acc, 16); sp_acc += __shfl_xor(sp_acc, 32);
  sn_acc += __shfl_xor(sn_acc, 16); sn_acc += __shfl_xor(sn_acc, 32);
  float rlp = 1.f / sp_acc, rln = 1.f / sn_acc;
  long obase = ((long)(tw + r) * 4 + b) * 1024 + h * 64;
#pragma unroll
  for (int dblk = 0; dblk < 4; dblk++) {
    float rl = (dblk < 2) ? rlp : rln;
    bf16x4 ov;
#pragma unroll
    for (int j = 0; j < 4; j++) ov[j] = (bf16)(o[dblk][j] * rl);
    *(bf16x4*)&attn_b[obase + (dblk >> 1) * 32 + (dblk & 1) * 16 + g * 4] = ov;
  }
}

// ---------------- launcher ----------------
extern "C" void kernel_launch(void* const* d_in, const int* in_sizes, int n_in,
                              void* d_out, int out_size, void* d_ws, size_t ws_size,
                              hipStream_t stream) {
  (void)in_sizes; (void)n_in; (void)out_size; (void)ws_size;
  const float* query = (const float*)d_in[0];
  const float* key   = (const float*)d_in[1];
  const float* value = (const float*)d_in[2];
  const float* W     = (const float*)d_in[3];
  const float* bias  = (const float*)d_in[4];
  const float* out_w = (const float*)d_in[5];
  const float* out_b = (const float*)d_in[6];

  char* ws = (char*)d_ws;
  const long MB = 1 << 20;
  bf16* qh  = (bf16*)(ws + 0 * MB);
  bf16* kh  = (bf16*)(ws + 8 * MB);
  bf16* vf  = (bf16*)(ws + 24 * MB);
  bf16* ab  = (bf16*)(ws + 32 * MB);
  bf16* WT  = (bf16*)(ws + 40 * MB);
  bf16* owb = (bf16*)(ws + 46 * MB);
  // overlays (dead-interval reuse; see header comment)
  bf16* qin = (bf16*)(ws + 16 * MB);
  bf16* kin = (bf16*)(ws + 32 * MB);
  bf16* vin = (bf16*)((char*)d_out + 16 * MB);
  float* out_attn = (float*)d_out;
  float* out_avg  = (float*)d_out + (size_t)4 * 1024 * 1024;

  // fused prep: q/k/v bf16 conversion + W transpose + out_w conversion
  prep_all<<<dim3(14080), 256, 0, stream>>>(query, key, value, W, out_w,
                                            qin, kin, vin, WT, owb);

  // projections: q,k -> head-major qh/kh; v -> vf fragment layout
  gemm_proj<<<dim3(8, 32, 3), 512, 0, stream>>>(qin, kin, vin, WT, bias, qh, vf);

  // fused: attention (blocks 0..1023) + avg_w GEMM (blocks 1024..1535)
  attn_avg<<<dim3(1536), 256, 0, stream>>>(qh, kh, vf, ab, out_avg,
                                           1.f / (16.f * LOG2E));

  // out projection: C = attn @ out_w^T + out_b
  gemm_out<<<dim3(8, 32), 512, 0, stream>>>(ab, owb, out_attn, out_b);
}

// Round 19
// 103.784 us; speedup vs baseline: 1.0953x; 1.0953x over previous
//
#include <hip/hip_runtime.h>
#include <hip/hip_bf16.h>

// Problem constants: E=1024, H=16, HD=64, T=1024, B=4, S=1024.
// d_out: attn(T,B,E) f32 [4M floats] then avg_w(B,T,S) f32 [4M floats].
// ws layout (bytes): qh 0..8M (head-major [bh][t][64], q pre-scaled 0.125*log2e),
//   kh 8..16M, vf 24..32M (frag-swizzled V, proj cmode3 LDS-coalesced epilogue),
//   ab 32..40M, WT 40..46M, owb 46..48M.
// q/k/v f32 inputs consumed DIRECTLY by gemm_proj via global_load_lds into f32
// LDS tiles (DMA path; conversion at fragment-read). avg_w computed inside the
// attn launch (blocks >= 1024) for overlap.

typedef __bf16 bf16;
typedef float f32x4 __attribute__((ext_vector_type(4)));
typedef float float4v __attribute__((ext_vector_type(4)));
typedef bf16 bf16x8 __attribute__((ext_vector_type(8)));
typedef bf16 bf16x4 __attribute__((ext_vector_type(4)));

#define LOG2E 1.4426950408889634f

// async global->LDS, 16B/lane; dst base wave-uniform (HW adds lane*16).
__device__ __forceinline__ void gll16(const void* g, void* l) {
  __builtin_amdgcn_global_load_lds(
      (const __attribute__((address_space(1))) void*)g,
      (__attribute__((address_space(3))) void*)l, 16, 0, 0);
}

// XCD-chunked swizzle: consecutive works (sharing an A-panel) land on one XCD.
__device__ __forceinline__ int xcd_swz(int flat, int nwg) {
  int q = nwg >> 3;
  return (flat & 7) * q + (flat >> 3);
}

__device__ __forceinline__ bf16x4 cvt4(float4v v) {
  bf16x4 b = { (bf16)v.x, (bf16)v.y, (bf16)v.z, (bf16)v.w };
  return b;
}

// ---------------- prep kernel (W transpose + out_w conv only) ----------------
__global__ __launch_bounds__(256) void prep_all(
    const float* __restrict__ W, const float* __restrict__ out_w,
    bf16* __restrict__ WT, bf16* __restrict__ owb) {
  __shared__ bf16 tile[64][72];
  int bid = blockIdx.x;
  if (bid >= 768) {  // out_w conversion: 1024 blocks
    int i = ((bid - 768) * 256 + (int)threadIdx.x) * 4;
    float4v v = *(const float4v*)(out_w + i);
    *(bf16x4*)&owb[i] = cvt4(v);
    return;
  }
  // W transpose: dst[sec][j][i] = (bf16) src[sec*1024 + i][j]
  int sec = bid >> 8, bx = bid & 15, by = (bid >> 4) & 15;
  int i0 = by * 64, j0 = bx * 64;
  const float* s = W + (long)sec * 1048576;
  bf16* d = WT + (long)sec * 1048576;
  int t = threadIdx.x;
#pragma unroll
  for (int p = 0; p < 4; p++) {
    int ri = (t >> 4) + p * 16, cj = (t & 15) * 4;
    float4v vv = *(const float4v*)(s + (long)(i0 + ri) * 1024 + j0 + cj);
    *(bf16x4*)&tile[ri][cj] = cvt4(vv);
  }
  __syncthreads();
#pragma unroll
  for (int p = 0; p < 4; p++) {
    int rj = (t >> 4) + p * 16, ci = (t & 15) * 4;
    bf16x4 bv = { tile[ci][rj], tile[ci + 1][rj], tile[ci + 2][rj], tile[ci + 3][rj] };
    *(bf16x4*)&d[(long)(j0 + rj) * 1024 + i0 + ci] = bv;
  }
}

// ---------------- unified NT GEMM core (512 thr, 8 waves, 128x128) ----------
// R11-best loop: double-buffered, stage(next) issued BEFORE compute(cur), ONE
// __syncthreads per k-step; ALL staging via global_load_lds (DMA, off the
// critical path). AF32: A is f32 in global, staged into f32 LDS tiles
// ([2][128x32]f32, 32KB) with pair-XOR swizzle (pair ^= row&3) applied on the
// SOURCE address + fragment READ; converted f32->bf16 at read (8 cvt_pk/step).
// LDS: AF32 48KB (3 blk/CU = proj grid residency), else 32KB.
// cmode: 0 f32 std, 1 bf16 std, 2 bf16 head-major, 3 vf fragment (LDS epi).
template <bool AF32>
__device__ __forceinline__ void gemm_core(
    const void* __restrict__ Av, long lda,
    const bf16* __restrict__ B, long ldb,
    void* __restrict__ C, long ldc,
    const float* __restrict__ bias, float scale, int K,
    int m0, int n0, int cmode) {
  __shared__ bf16 smem[AF32 ? 24576 : 16384];
  float* sAf = (float*)smem;                       // AF32: [2][4096] f32
  bf16* sBb = smem + (AF32 ? 16384 : 8192);        // [2][4096] bf16
  int t = threadIdx.x;
  int w = t >> 6, lane = t & 63, r = lane & 15, g = lane >> 4;
  int mq = (w >> 1) * 32, nq = (w & 1) * 64;
  int srow = w * 16 + (lane >> 2);
  int scol = ((lane & 3) ^ ((srow >> 1) & 3)) * 8;
  int fsw = (r >> 1) & 3;
  const bf16* Bs = B + (long)(n0 + srow) * ldb + scol;
  const bf16* As = (const bf16*)Av + (long)(m0 + srow) * lda + scol;  // !AF32
  // AF32 staging addresses: lane l stages row w*16 + (l>>3) (+8 on 2nd gll),
  // stored pair (l>>1)&3 holds logical pair ((l>>1)&3) ^ (row&3).
  int aro = lane >> 3;
  int acolf = 8 * (((lane >> 1) & 3) ^ (aro & 3)) + 4 * (lane & 1);
  const float* Af = (const float*)Av + (long)(m0 + w * 16 + aro) * lda + acolf;

  f32x4 acc[2][4];
#pragma unroll
  for (int mi = 0; mi < 2; mi++)
#pragma unroll
    for (int ni = 0; ni < 4; ni++) acc[mi][ni] = (f32x4){0.f, 0.f, 0.f, 0.f};

  auto stage = [&](int buf, int k) {
    if (AF32) {
      gll16(Af + k, sAf + buf * 4096 + w * 512);
      gll16(Af + 8 * lda + k, sAf + buf * 4096 + w * 512 + 256);
    } else {
      gll16(As + k, &smem[buf * 4096 + w * 512]);
    }
    gll16(Bs + k, &sBb[buf * 4096 + w * 512]);
  };
  stage(0, 0);
  __syncthreads();
  int cur = 0;
  for (int k0 = 0; k0 < K; k0 += 32) {
    if (k0 + 32 < K) stage(cur ^ 1, k0 + 32);
    bf16x8 af[2], bfr[4];
    if (AF32) {
      int key2 = r & 3;
#pragma unroll
      for (int mi = 0; mi < 2; mi++) {
        int row = mq + mi * 16 + r;
        const float* pa = sAf + cur * 4096 + row * 32 + 8 * (g ^ key2);
        float4v lo = *(const float4v*)pa;
        float4v hi = *(const float4v*)(pa + 4);
        bf16x4 l4 = cvt4(lo), h4 = cvt4(hi);
        bf16x8 a = { l4[0], l4[1], l4[2], l4[3], h4[0], h4[1], h4[2], h4[3] };
        af[mi] = a;
      }
    } else {
#pragma unroll
      for (int mi = 0; mi < 2; mi++)
        af[mi] = *(bf16x8*)&smem[cur * 4096 + (mq + mi * 16 + r) * 32 + 8 * (g ^ fsw)];
    }
#pragma unroll
    for (int ni = 0; ni < 4; ni++)
      bfr[ni] = *(bf16x8*)&sBb[cur * 4096 + (nq + ni * 16 + r) * 32 + 8 * (g ^ fsw)];
#pragma unroll
    for (int mi = 0; mi < 2; mi++)
#pragma unroll
      for (int ni = 0; ni < 4; ni++)
        acc[mi][ni] = __builtin_amdgcn_mfma_f32_16x16x32_bf16(af[mi], bfr[ni], acc[mi][ni], 0, 0, 0);
    __syncthreads();
    cur ^= 1;
  }

  if (cmode == 3) {
    // acc -> LDS in vf order -> coalesced 1KB/wave stores (R15-verified map).
#pragma unroll
    for (int mi = 0; mi < 2; mi++) {
      int s32 = (mq >> 2) + mi * 4 + g;
      int gq = (s32 >> 2) & 3;
      int u = ((s32 >> 4) << 2) | (s32 & 3);
#pragma unroll
      for (int ni = 0; ni < 4; ni++) {
        int col = n0 + nq + ni * 16 + r;
        float bv = bias ? bias[col] : 0.f;
        int clbase = ((nq >> 5) + (ni >> 1)) * 2 + (ni & 1);
#pragma unroll
        for (int j = 0; j < 4; j++) {
          float val = (acc[mi][ni][j] + bv) * scale;
          smem[(j * 8 + clbase) * 512 + (gq * 16 + r) * 8 + u] = (bf16)val;
        }
      }
    }
    __syncthreads();
    int sc_ = m0 >> 7;
    int hh0 = (n0 & 511) >> 5;
    int half = n0 >> 9;
#pragma unroll
    for (int c = 0; c < 4; c++) {
      int cl = w * 4 + c;
      int b_ = cl >> 3, hl = (cl >> 1) & 3, dl = cl & 1;
      long chunk = ((long)(b_ * 16 + hh0 + hl) * 32 + sc_) * 4 + half * 2 + dl;
      bf16x8 v = *(bf16x8*)&smem[cl * 512 + lane * 8];
      *(bf16x8*)&((bf16*)C)[(chunk << 9) + lane * 8] = v;
    }
    return;
  }

#pragma unroll
  for (int mi = 0; mi < 2; mi++)
#pragma unroll
    for (int ni = 0; ni < 4; ni++) {
      int col = n0 + nq + ni * 16 + r;
      float bv = bias ? bias[col] : 0.f;
#pragma unroll
      for (int j = 0; j < 4; j++) {
        int row = m0 + mq + mi * 16 + g * 4 + j;
        float val = (acc[mi][ni][j] + bv) * scale;
        if (cmode == 2) {
          int bb = row & 3, tt = row >> 2, hh = col >> 6, dd = col & 63;
          ((bf16*)C)[((long)(bb * 16 + hh) * 1024 + tt) * 64 + dd] = (bf16)val;
        } else if (cmode == 1) {
          ((bf16*)C)[(long)row * ldc + col] = (bf16)val;
        } else {
          ((float*)C)[(long)row * ldc + col] = val;
        }
      }
    }
}

// out-projection (bf16 A, cmode 0)
__global__ __launch_bounds__(512) void gemm_out(
    const bf16* __restrict__ A, const bf16* __restrict__ B,
    float* __restrict__ C, const float* __restrict__ bias) {
  int nwg = gridDim.x * gridDim.y;
  int flat = blockIdx.x + gridDim.x * blockIdx.y;
  int work = xcd_swz(flat, nwg);
  int n = work % gridDim.x, m = work / gridDim.x;
  gemm_core<false>(A, 1024, B, 1024, C, 1024, bias, 1.0f, 1024, m * 128, n * 128, 0);
}

// fused q/k/v projection straight from f32 inputs (gll-DMA staged);
// v (z=2) writes vf fragment layout (cmode 3)
__global__ __launch_bounds__(512) void gemm_proj(
    const float* __restrict__ q, const float* __restrict__ k,
    const float* __restrict__ v, const bf16* __restrict__ WT,
    const float* __restrict__ bias, bf16* __restrict__ qkout,
    bf16* __restrict__ vf) {
  int nwg = gridDim.x * gridDim.y * gridDim.z;
  int flat = blockIdx.x + gridDim.x * (blockIdx.y + gridDim.y * blockIdx.z);
  int work = xcd_swz(flat, nwg);
  int n = work % gridDim.x;
  int m = (work / gridDim.x) % gridDim.y;
  int z = work / (gridDim.x * gridDim.y);
  const float* A = (z == 0) ? q : ((z == 1) ? k : v);
  const bf16* B = WT + (long)z * 1048576;
  const float* bz = bias + z * 1024;
  void* C = (z == 2) ? (void*)vf : (void*)(qkout + (long)z * 4194304);
  float scale = (z == 0) ? 0.125f * LOG2E : 1.0f;
  gemm_core<true>(A, 1024, B, 1024, C, 1024, bz, scale, 1024, m * 128, n * 128,
                  z == 2 ? 3 : 2);
}

// ---------------- fused attention + avg_w (one launch, 256 thr) -------------
// blocks [0,1024): attn v12 (bh = bid%64, t0 = bid/64).
// blocks [1024,1536): avg_w 64x128-tile GEMM over head-major qh/kh.
// Shared 32KB LDS arena unioned across the two bodies -> 5 blocks/CU.
__global__ __launch_bounds__(256) void attn_avg(
    const bf16* __restrict__ qh, const bf16* __restrict__ kh,
    const bf16* __restrict__ vf, bf16* __restrict__ attn_b,
    float* __restrict__ out_avg, float avg_scale) {
  __shared__ __align__(16) bf16 smem[16384];  // 32 KB arena
  int tid = threadIdx.x, w = tid >> 6, lane = tid & 63, r = lane & 15, g = lane >> 4;
  int fsw = (r >> 1) & 3;

  if (blockIdx.x >= 1024) {
    // ---------- avg_w: C[bb][t][s] = avg_scale * sum_e qh[t][e] kh[s][e] ----
    bf16* sA = smem;            // [2][2048]
    bf16* sB = smem + 4096;     // [2][4096]
    int work = xcd_swz(blockIdx.x - 1024, 512);
    int n0 = (work & 7) * 128;
    int m0 = ((work >> 3) & 15) * 64;
    int bb = work >> 7;
    int mq = (w >> 1) * 32, nq = (w & 1) * 64;
    int srow = w * 16 + (lane >> 2);            // 0..63
    int scol = ((lane & 3) ^ ((srow >> 1) & 3)) * 8;
    const bf16* Asb = qh + (long)bb * 1048576 + (long)(m0 + srow) * 64 + scol;
    const bf16* Bs0 = kh + (long)bb * 1048576 + (long)(n0 + srow) * 64 + scol;
    const bf16* Bs1 = kh + (long)bb * 1048576 + (long)(n0 + srow + 64) * 64 + scol;

    f32x4 acc[2][4];
#pragma unroll
    for (int mi = 0; mi < 2; mi++)
#pragma unroll
      for (int ni = 0; ni < 4; ni++) acc[mi][ni] = (f32x4){0.f, 0.f, 0.f, 0.f};

    auto stage = [&](int buf, long off) {
      gll16(Asb + off, &sA[buf * 2048 + w * 512]);
      gll16(Bs0 + off, &sB[buf * 4096 + w * 512]);
      gll16(Bs1 + off, &sB[buf * 4096 + 2048 + w * 512]);
    };
    stage(0, 0);
    __syncthreads();
    int cur = 0;
    for (int k0 = 0; k0 < 1024; k0 += 32) {
      if (k0 + 32 < 1024) {
        int kn = k0 + 32;
        stage(cur ^ 1, ((long)(kn >> 6)) * 65536 + (kn & 63));
      }
      bf16x8 af[2], bfr[4];
#pragma unroll
      for (int mi = 0; mi < 2; mi++)
        af[mi] = *(bf16x8*)&sA[cur * 2048 + (mq + mi * 16 + r) * 32 + 8 * (g ^ fsw)];
#pragma unroll
      for (int ni = 0; ni < 4; ni++)
        bfr[ni] = *(bf16x8*)&sB[cur * 4096 + (nq + ni * 16 + r) * 32 + 8 * (g ^ fsw)];
#pragma unroll
      for (int mi = 0; mi < 2; mi++)
#pragma unroll
        for (int ni = 0; ni < 4; ni++)
          acc[mi][ni] = __builtin_amdgcn_mfma_f32_16x16x32_bf16(af[mi], bfr[ni], acc[mi][ni], 0, 0, 0);
      __syncthreads();
      cur ^= 1;
    }
#pragma unroll
    for (int mi = 0; mi < 2; mi++)
#pragma unroll
      for (int ni = 0; ni < 4; ni++) {
        int col = n0 + nq + ni * 16 + r;
#pragma unroll
        for (int j = 0; j < 4; j++) {
          int row = m0 + mq + mi * 16 + g * 4 + j;
          out_avg[(long)bb * 1048576 + (long)row * 1024 + col] = acc[mi][ni][j] * avg_scale;
        }
      }
    return;
  }

  // ---------- attn (v12): 4 waves, 16 t-rows/wave, full-S sweep ----------
  bf16* sK = smem;            // [2][4096]
  bf16* sV = smem + 8192;     // [2][4096]
  int bh = blockIdx.x & 63;
  int b = bh >> 4, h = bh & 15;
  int t0 = (blockIdx.x >> 6) * 64;
  int tw = t0 + w * 16;

  const bf16* qrow = qh + ((long)bh * 1024 + tw + r) * 64;
  bf16x8 aq0 = *(const bf16x8*)(qrow + g * 8);
  bf16x8 aq1 = *(const bf16x8*)(qrow + 32 + g * 8);

  float sp_acc = 0.f, sn_acc = 0.f;
  f32x4 o[4];
#pragma unroll
  for (int d = 0; d < 4; d++) o[d] = (f32x4){0.f, 0.f, 0.f, 0.f};

  const bf16* kbh = kh + (long)bh * 65536;
  const bf16* vbh = vf + (long)bh * 65536;

  int krow = w * 16 + (lane >> 3);
  const bf16* ksrc = kbh + (long)krow * 64 + 8 * ((lane & 7) ^ (krow & 7));
  const bf16* vsrc = vbh + w * 1024 + lane * 8;
  int c0 = 8 * (g ^ (r & 7));
  int c1 = 8 * ((g + 4) ^ (r & 7));

  auto stage = [&](int buf, int st) {
    const bf16* kp = ksrc + st * 4096;
    gll16(kp, &sK[buf * 4096 + w * 1024]);
    gll16(kp + 512, &sK[buf * 4096 + w * 1024 + 512]);
    const bf16* vp = vsrc + st * 4096;
    gll16(vp, &sV[buf * 4096 + w * 1024]);
    gll16(vp + 512, &sV[buf * 4096 + w * 1024 + 512]);
  };
  stage(0, 0);
  __syncthreads();
  int cur = 0;
#pragma unroll 1
  for (int st = 0; st < 16; st++) {
    if (st < 15) stage(cur ^ 1, st + 1);
    f32x4 sc4[4];
#pragma unroll
    for (int sf = 0; sf < 4; sf++) {
      int row = sf * 16 + r;
      bf16x8 k0 = *(const bf16x8*)&sK[cur * 4096 + row * 64 + c0];
      bf16x8 k1 = *(const bf16x8*)&sK[cur * 4096 + row * 64 + c1];
      f32x4 z = (f32x4){0.f, 0.f, 0.f, 0.f};
      z = __builtin_amdgcn_mfma_f32_16x16x32_bf16(k0, aq0, z, 0, 0, 0);
      z = __builtin_amdgcn_mfma_f32_16x16x32_bf16(k1, aq1, z, 0, 0, 0);
      sc4[sf] = z;
    }
    bf16x8 pP[2], pN[2];
#pragma unroll
    for (int sf = 0; sf < 4; sf++)
#pragma unroll
      for (int j = 0; j < 4; j++) {
        float e = __builtin_amdgcn_exp2f(sc4[sf][j]);
        sp_acc += e;
        pP[sf >> 1][(sf & 1) * 4 + j] = (bf16)e;
        float f = __builtin_amdgcn_exp2f(-sc4[sf][j]);
        sn_acc += f;
        pN[sf >> 1][(sf & 1) * 4 + j] = (bf16)f;
      }
#pragma unroll
    for (int c = 0; c < 2; c++)
#pragma unroll
      for (int dblk = 0; dblk < 4; dblk++) {
        bf16x8 vv = *(const bf16x8*)&sV[cur * 4096 + (c * 4 + dblk) * 512 + lane * 8];
        o[dblk] = __builtin_amdgcn_mfma_f32_16x16x32_bf16(
            vv, (dblk < 2) ? pP[c] : pN[c], o[dblk], 0, 0, 0);
      }
    __syncthreads();
    cur ^= 1;
  }

  sp_acc += __shfl_xor(sp_acc, 16); sp_acc += __shfl_xor(sp_acc, 32);
  sn_acc += __shfl_xor(sn_acc, 16); sn_acc += __shfl_xor(sn_acc, 32);
  float rlp = 1.f / sp_acc, rln = 1.f / sn_acc;
  long obase = ((long)(tw + r) * 4 + b) * 1024 + h * 64;
#pragma unroll
  for (int dblk = 0; dblk < 4; dblk++) {
    float rl = (dblk < 2) ? rlp : rln;
    bf16x4 ov;
#pragma unroll
    for (int j = 0; j < 4; j++) ov[j] = (bf16)(o[dblk][j] * rl);
    *(bf16x4*)&attn_b[obase + (dblk >> 1) * 32 + (dblk & 1) * 16 + g * 4] = ov;
  }
}

// ---------------- launcher ----------------
extern "C" void kernel_launch(void* const* d_in, const int* in_sizes, int n_in,
                              void* d_out, int out_size, void* d_ws, size_t ws_size,
                              hipStream_t stream) {
  (void)in_sizes; (void)n_in; (void)out_size; (void)ws_size;
  const float* query = (const float*)d_in[0];
  const float* key   = (const float*)d_in[1];
  const float* value = (const float*)d_in[2];
  const float* W     = (const float*)d_in[3];
  const float* bias  = (const float*)d_in[4];
  const float* out_w = (const float*)d_in[5];
  const float* out_b = (const float*)d_in[6];

  char* ws = (char*)d_ws;
  const long MB = 1 << 20;
  bf16* qh  = (bf16*)(ws + 0 * MB);
  bf16* kh  = (bf16*)(ws + 8 * MB);
  bf16* vf  = (bf16*)(ws + 24 * MB);
  bf16* ab  = (bf16*)(ws + 32 * MB);
  bf16* WT  = (bf16*)(ws + 40 * MB);
  bf16* owb = (bf16*)(ws + 46 * MB);
  float* out_attn = (float*)d_out;
  float* out_avg  = (float*)d_out + (size_t)4 * 1024 * 1024;

  // prep: W transpose + out_w conversion only (q/k/v consumed directly by proj)
  prep_all<<<dim3(1792), 256, 0, stream>>>(W, out_w, WT, owb);

  // projections straight from f32 inputs: q,k -> head-major; v -> vf fragment
  gemm_proj<<<dim3(8, 32, 3), 512, 0, stream>>>(query, key, value, WT, bias, qh, vf);

  // fused: attention (blocks 0..1023) + avg_w GEMM (blocks 1024..1535)
  attn_avg<<<dim3(1536), 256, 0, stream>>>(qh, kh, vf, ab, out_avg,
                                           1.f / (16.f * LOG2E));

  // out projection: C = attn @ out_w^T + out_b
  gemm_out<<<dim3(8, 32), 512, 0, stream>>>(ab, owb, out_attn, out_b);
}